// Round 9
// baseline (124.400 us; speedup 1.0000x reference)
//
#include <hip/hip_runtime.h>
#include <math.h>

#ifndef __has_builtin
#define __has_builtin(x) 0
#endif

#define NPTS   131072
#define FCH    16
#define CSND   343.0f
#define PB     32           // points per pass
#define BLOCK  256          // 4 waves
#define GRID   512          // 2 WG/CU * 256 CUs, persistent
#define NBLK   (NPTS / PB)  // 4096

typedef _Float16 half8 __attribute__((ext_vector_type(8)));
typedef _Float16 half2v __attribute__((ext_vector_type(2)));
typedef float    f32x4 __attribute__((ext_vector_type(4)));

static __device__ __forceinline__ unsigned pack2(float a, float b) {
#if __has_builtin(__builtin_amdgcn_cvt_pkrtz)
  return __builtin_bit_cast(unsigned, __builtin_amdgcn_cvt_pkrtz(a, b));
#else
  half2v v; v[0] = (_Float16)a; v[1] = (_Float16)b;
  return __builtin_bit_cast(unsigned, v);
#endif
}

// tanh(x) = 1 - 2/(e^{2x}+1): 5 VALU ops, monotone-correct at +/-inf.
static __device__ __forceinline__ float mytanh(float x) {
#if __has_builtin(__builtin_amdgcn_exp2f)
  float e = __builtin_amdgcn_exp2f(2.885390082f * x);   // 2*log2(e)*x
#else
  float e = __expf(2.0f * x);
#endif
  return fmaf(-2.0f, __builtin_amdgcn_rcpf(e + 1.0f), 1.0f);
}

// PB=32, single-buffered, 56 KB LDS -> 2 WG/CU:
//   s_A[160][64] dw : A f16, rows R = v*32 + p (v=0..4: h1,d0,d1,d2,c1; p=0..31),
//                     chunk c (4 dw = 8 units) stored at (c ^ (R&15))
//   s_HG[32][128] dw: point p: h2-halves dwords [p*128..+63], G [p*128+64..+127].
//                     dword q = 32*nh + 16*pr + col holds pack2(ntl=2pr, 2pr+1),
//                     j(kappa) = 64*nh + 32*pr + 16*(kappa&1) + col; chunk-swizzled
//                     (cq ^ (p&15)). W3 rows permuted identically when loading w3f.
// Phase B: wave w owns quadrant (ph = w>>1: points 16ph..+15, nh = w&1: cols
//   64nh..+63). Each A-frag read feeds 4 MFMAs (4 n-tiles) -> B-reads halved.
// Phase D: all 4 waves: m-tile ph, n-tile nh (re/im); residual in-lane.
// Loop: [D(i-1)] A(i) |b1| B(i),C(i) |b2|. Hazards: D(i-1) rd HG vs C(i) wr HG
//   span b1; A(i) wr s_A vs B(i-1) rd span b2(i-1); B(i) rd vs A(i) wr span b1.

__global__ __launch_bounds__(BLOCK, 2) void helmholtz_kernel(
    const float* __restrict__ x,      // [N,3]
    const float* __restrict__ omega,  // [16]
    const float* __restrict__ W1,     // [3,128]
    const float* __restrict__ b1,     // [128]
    const float* __restrict__ W2,     // [128,128]
    const float* __restrict__ b2,     // [128]
    const float* __restrict__ W3,     // [128,32]
    const float* __restrict__ b3,     // [32]
    float* __restrict__ out)
{
  __shared__ unsigned s_A[160 * 64];   // 40 KB
  __shared__ unsigned s_HG[32 * 128];  // 16 KB

  const int tid  = threadIdx.x;
  const int w    = tid >> 6;   // wave 0..3
  const int l    = tid & 63;
  const int col  = l & 15;
  const int quad = l >> 4;
  const int ph   = w >> 1;     // point-half (B and D m-tile)
  const int nh   = w & 1;      // n-half (B); re/im tile (D)

  // ---- phase A task: points pA, pA+16; units 8g..8g+7 ----
  const int pA = tid >> 4;
  const int g  = tid & 15;
  float wx[8], wy[8], wz[8], bB[8], wq[8];
#pragma unroll
  for (int u = 0; u < 8; u++) {
    int unit = 8 * g + u;
    wx[u] = W1[unit]; wy[u] = W1[128 + unit]; wz[u] = W1[256 + unit];
    bB[u] = b1[unit];
    wq[u] = wx[u] * wx[u] + wy[u] * wy[u] + wz[u] * wz[u];
  }

  // ---- W2^T fragments: 4 n-tiles (cols 64*nh + 16*t4 + col), 64 VGPRs ----
  half8 w2f[4][4];
#pragma unroll
  for (int t4 = 0; t4 < 4; t4++) {
    const int n = 64 * nh + 16 * t4 + col;
#pragma unroll
    for (int ks = 0; ks < 4; ks++) {
      half8 f;
#pragma unroll
      for (int j8 = 0; j8 < 8; j8++)
        f[j8] = (_Float16)W2[(ks * 32 + (quad << 3) + j8) * 128 + n];
      w2f[t4][ks] = f;
    }
  }
  // ---- W3^T fragment, j-permuted to match HG layout (16 VGPRs) ----
  half8 w3f[4];
#pragma unroll
  for (int ks = 0; ks < 4; ks++) {
    half8 f;
#pragma unroll
    for (int j8 = 0; j8 < 8; j8++) {
      int kap = ks * 32 + (quad << 3) + j8;
      int q   = kap >> 1;
      int j   = 64 * (q >> 5) + 32 * ((q >> 4) & 1) + 16 * (kap & 1) + (q & 15);
      f[j8] = (_Float16)W3[j * 32 + 16 * nh + col];
    }
    w3f[ks] = f;
  }

  float b2r[4];
#pragma unroll
  for (int t4 = 0; t4 < 4; t4++) b2r[t4] = b2[64 * nh + 16 * t4 + col];
  float k2v = 0.0f;
  if (col >= 1) {
    float om = omega[col] * (1.0f / CSND);
    k2v = om * om;
  }
  const float b3v = b3[16 * nh + col];

  float wsum = 0.0f;
  float xr[2][3];

  auto loadX = [&](int blk) {
    const float* xb = x + (size_t)blk * PB * 3;
#pragma unroll
    for (int hp = 0; hp < 2; hp++) {
      int p = pA + 16 * hp;
      xr[hp][0] = xb[3 * p]; xr[hp][1] = xb[3 * p + 1]; xr[hp][2] = xb[3 * p + 2];
    }
  };

  auto phaseA = [&]() {
    const int cbase = (g ^ pA) << 2;
#pragma unroll
    for (int hp = 0; hp < 2; hp++) {
      int p = pA + 16 * hp;
      float x0 = xr[hp][0], x1 = xr[hp][1], x2 = xr[hp][2];
      float t[8], s[8];
#pragma unroll
      for (int u = 0; u < 8; u++) {
        float z = fmaf(x0, wx[u], fmaf(x1, wy[u], fmaf(x2, wz[u], bB[u])));
        t[u] = mytanh(z);
        s[u] = 1.0f - t[u] * t[u];
      }
      uint4 q;
      q = make_uint4(pack2(t[0], t[1]), pack2(t[2], t[3]),
                     pack2(t[4], t[5]), pack2(t[6], t[7]));
      *(uint4*)&s_A[(p)       * 64 + cbase] = q;
      q = make_uint4(pack2(s[0]*wx[0], s[1]*wx[1]), pack2(s[2]*wx[2], s[3]*wx[3]),
                     pack2(s[4]*wx[4], s[5]*wx[5]), pack2(s[6]*wx[6], s[7]*wx[7]));
      *(uint4*)&s_A[(32 + p)  * 64 + cbase] = q;
      q = make_uint4(pack2(s[0]*wy[0], s[1]*wy[1]), pack2(s[2]*wy[2], s[3]*wy[3]),
                     pack2(s[4]*wy[4], s[5]*wy[5]), pack2(s[6]*wy[6], s[7]*wy[7]));
      *(uint4*)&s_A[(64 + p)  * 64 + cbase] = q;
      q = make_uint4(pack2(s[0]*wz[0], s[1]*wz[1]), pack2(s[2]*wz[2], s[3]*wz[3]),
                     pack2(s[4]*wz[4], s[5]*wz[5]), pack2(s[6]*wz[6], s[7]*wz[7]));
      *(uint4*)&s_A[(96 + p)  * 64 + cbase] = q;
      float c[8];
#pragma unroll
      for (int u = 0; u < 8; u++) c[u] = -2.0f * t[u] * s[u] * wq[u];
      q = make_uint4(pack2(c[0], c[1]), pack2(c[2], c[3]),
                     pack2(c[4], c[5]), pack2(c[6], c[7]));
      *(uint4*)&s_A[(128 + p) * 64 + cbase] = q;
    }
  };

  auto phaseDE = [&]() {
    const int pbase = (16 * ph + col) * 128;   // point row; (row&15)=col swizzle
    f32x4 dy = (f32x4){0.0f, 0.0f, 0.0f, 0.0f};
    f32x4 dl = (f32x4){0.0f, 0.0f, 0.0f, 0.0f};
#pragma unroll
    for (int ks = 0; ks < 4; ks++) {
      int pos = ((((ks << 2) + quad) ^ col) << 2);
      half8 afy = *(const half8*)&s_HG[pbase + pos];
      half8 afl = *(const half8*)&s_HG[pbase + 64 + pos];
      dy = __builtin_amdgcn_mfma_f32_16x16x32_f16(afy, w3f[ks], dy, 0, 0, 0);
      dl = __builtin_amdgcn_mfma_f32_16x16x32_f16(afl, w3f[ks], dl, 0, 0, 0);
    }
    if (col >= 1) {
#pragma unroll
      for (int r = 0; r < 4; r++) {
        float yv  = dy[r] + b3v;
        float res = fmaf(k2v, yv, dl[r]);
        wsum += res * res;
      }
    }
  };

  // ---- main loop ----
  loadX(blockIdx.x);
  bool first = true;
  for (int blk = blockIdx.x; blk < NBLK; blk += gridDim.x) {
    if (!first) phaseDE();          // D(i-1): reads s_HG (pre-b1)
    first = false;
    phaseA();                       // writes s_A
    __syncthreads();                // b1

    int nblk = blk + (int)gridDim.x;
    if (nblk < NBLK) loadX(nblk);   // prefetch x for next pass

    // ---- B(i): quadrant GEMM, A-frag feeds 4 MFMAs ----
    f32x4 acc[5][4];
#pragma unroll
    for (int v = 0; v < 5; v++)
#pragma unroll
      for (int t4 = 0; t4 < 4; t4++)
        acc[v][t4] = (f32x4){0.0f, 0.0f, 0.0f, 0.0f};

#pragma unroll
    for (int v = 0; v < 5; v++) {
      const int rb = (v * 32 + 16 * ph + col) * 64;
#pragma unroll
      for (int ks = 0; ks < 4; ks++) {
        half8 af = *(const half8*)&s_A[rb + ((((ks << 2) + quad) ^ col) << 2)];
        acc[v][0] = __builtin_amdgcn_mfma_f32_16x16x32_f16(af, w2f[0][ks], acc[v][0], 0, 0, 0);
        acc[v][1] = __builtin_amdgcn_mfma_f32_16x16x32_f16(af, w2f[1][ks], acc[v][1], 0, 0, 0);
        acc[v][2] = __builtin_amdgcn_mfma_f32_16x16x32_f16(af, w2f[2][ks], acc[v][2], 0, 0, 0);
        acc[v][3] = __builtin_amdgcn_mfma_f32_16x16x32_f16(af, w2f[3][ks], acc[v][3], 0, 0, 0);
      }
    }

    // ---- C(i): layer-2 elementwise; paired-dword writes into permuted HG ----
#pragma unroll
    for (int r = 0; r < 4; r++) {
      int p = 16 * ph + (quad << 2) + r;
      float t2[4], gg[4];
#pragma unroll
      for (int t4 = 0; t4 < 4; t4++) {
        float z2 = acc[0][t4][r] + b2r[t4];
        float d0 = acc[1][t4][r], d1 = acc[2][t4][r], d2 = acc[3][t4][r];
        float Av = acc[4][t4][r];
        float t  = mytanh(z2);
        float s2 = 1.0f - t * t;
        t2[t4] = t;
        gg[t4] = s2 * (Av - 2.0f * t * (d0 * d0 + d1 * d1 + d2 * d2));
      }
      int pb = p * 128;
#pragma unroll
      for (int pr = 0; pr < 2; pr++) {
        int q   = 32 * nh + 16 * pr + col;
        int pos = (((q >> 2) ^ (p & 15)) << 2) + (q & 3);
        s_HG[pb + pos]      = pack2(t2[2 * pr], t2[2 * pr + 1]);
        s_HG[pb + 64 + pos] = pack2(gg[2 * pr], gg[2 * pr + 1]);
      }
    }
    __syncthreads();                // b2
  }
  phaseDE();                        // epilogue D for the final pass

  // ---- final: wave reduce, one atomic per wave ----
#pragma unroll
  for (int off = 32; off > 0; off >>= 1)
    wsum += __shfl_down(wsum, off, 64);
  if (l == 0)
    atomicAdd(out, wsum * (1.0f / ((float)NPTS * (float)(FCH - 1))));
}

extern "C" void kernel_launch(void* const* d_in, const int* in_sizes, int n_in,
                              void* d_out, int out_size, void* d_ws, size_t ws_size,
                              hipStream_t stream) {
  const float* x     = (const float*)d_in[0];
  const float* omega = (const float*)d_in[1];
  const float* W1    = (const float*)d_in[2];
  const float* b1    = (const float*)d_in[3];
  const float* W2    = (const float*)d_in[4];
  const float* b2    = (const float*)d_in[5];
  const float* W3    = (const float*)d_in[6];
  const float* b3    = (const float*)d_in[7];
  float* out = (float*)d_out;

  (void)hipMemsetAsync(out, 0, sizeof(float), stream);
  helmholtz_kernel<<<GRID, BLOCK, 0, stream>>>(x, omega, W1, b1, W2, b2, W3, b3, out);
}

// Round 10
// 120.442 us; speedup vs baseline: 1.0329x; 1.0329x over previous
//
#include <hip/hip_runtime.h>
#include <math.h>

#ifndef __has_builtin
#define __has_builtin(x) 0
#endif

#define NPTS   131072
#define FCH    16
#define CSND   343.0f
#define PB     32           // points per pass
#define BLOCK  256          // 4 waves
#define GRID   512          // 2 WG/CU * 256 CUs, persistent
#define NBLK   (NPTS / PB)  // 4096

typedef _Float16 half8 __attribute__((ext_vector_type(8)));
typedef _Float16 half2v __attribute__((ext_vector_type(2)));
typedef float    f32x4 __attribute__((ext_vector_type(4)));

static __device__ __forceinline__ unsigned pack2(float a, float b) {
#if __has_builtin(__builtin_amdgcn_cvt_pkrtz)
  return __builtin_bit_cast(unsigned, __builtin_amdgcn_cvt_pkrtz(a, b));
#else
  half2v v; v[0] = (_Float16)a; v[1] = (_Float16)b;
  return __builtin_bit_cast(unsigned, v);
#endif
}

// tanh(x) = 1 - 2/(e^{2x}+1): 5 VALU ops, monotone-correct at +/-inf.
static __device__ __forceinline__ float mytanh(float x) {
#if __has_builtin(__builtin_amdgcn_exp2f)
  float e = __builtin_amdgcn_exp2f(2.885390082f * x);   // 2*log2(e)*x
#else
  float e = __expf(2.0f * x);
#endif
  return fmaf(-2.0f, __builtin_amdgcn_rcpf(e + 1.0f), 1.0f);
}

// PB=32, single-buffered, 56 KB LDS -> 2 WG/CU:
//   s_A[160][64] dw : A f16, rows R = v*32 + p (v=0..4: h1,d0,d1,d2,c1; p=0..31),
//                     chunk c (4 dw = 8 units) stored at (c ^ (R&15))
//   s_HG[32][128] dw: point p: h2-halves dwords [p*128..+63], G [p*128+64..+127].
//                     dword q = 32*nh + 16*pr + col holds pack2(ntl=2pr, 2pr+1),
//                     chunk-swizzled (cq ^ (p&15)). w3f rows permuted to match.
// Phase B: wave w owns quadrant (ph = w>>1: points 16ph..+15, nh = w&1: cols
//   64nh..+63); STAGED: v=1..3 -> bsum (frees 48 regs), then v=0,4.
// Phase D: all 4 waves: m-tile ph, n-tile nh (re/im); residual in-lane.
// Loop: [D(i-1)] A(i) |b1| B(i),C(i) |b2|. Hazards: D(i-1) rd HG vs C(i) wr HG
//   span b1; A(i) wr s_A vs B(i-1) rd span b2(i-1); B(i) rd vs A(i) wr span b1.

__global__ __launch_bounds__(BLOCK, 2) void helmholtz_kernel(
    const float* __restrict__ x,      // [N,3]
    const float* __restrict__ omega,  // [16]
    const float* __restrict__ W1,     // [3,128]
    const float* __restrict__ b1,     // [128]
    const float* __restrict__ W2,     // [128,128]
    const float* __restrict__ b2,     // [128]
    const float* __restrict__ W3,     // [128,32]
    const float* __restrict__ b3,     // [32]
    float* __restrict__ out)
{
  __shared__ unsigned s_A[160 * 64];   // 40 KB
  __shared__ unsigned s_HG[32 * 128];  // 16 KB

  const int tid  = threadIdx.x;
  const int w    = tid >> 6;   // wave 0..3
  const int l    = tid & 63;
  const int col  = l & 15;
  const int quad = l >> 4;
  const int ph   = w >> 1;     // point-half (B and D m-tile)
  const int nh   = w & 1;      // n-half (B); re/im tile (D)

  // ---- phase A task: points pA, pA+16; units 8g..8g+7 ----
  const int pA = tid >> 4;
  const int g  = tid & 15;
  float wx[8], wy[8], wz[8], bB[8];
#pragma unroll
  for (int u = 0; u < 8; u++) {
    int unit = 8 * g + u;
    wx[u] = W1[unit]; wy[u] = W1[128 + unit]; wz[u] = W1[256 + unit];
    bB[u] = b1[unit];
  }

  // ---- W2^T fragments: 4 n-tiles (cols 64*nh + 16*t4 + col), 64 VGPRs ----
  half8 w2f[4][4];
#pragma unroll
  for (int t4 = 0; t4 < 4; t4++) {
    const int n = 64 * nh + 16 * t4 + col;
#pragma unroll
    for (int ks = 0; ks < 4; ks++) {
      half8 f;
#pragma unroll
      for (int j8 = 0; j8 < 8; j8++)
        f[j8] = (_Float16)W2[(ks * 32 + (quad << 3) + j8) * 128 + n];
      w2f[t4][ks] = f;
    }
  }
  // ---- W3^T fragment, j-permuted to match HG layout (16 VGPRs) ----
  half8 w3f[4];
#pragma unroll
  for (int ks = 0; ks < 4; ks++) {
    half8 f;
#pragma unroll
    for (int j8 = 0; j8 < 8; j8++) {
      int kap = ks * 32 + (quad << 3) + j8;
      int q   = kap >> 1;
      int j   = 64 * (q >> 5) + 32 * ((q >> 4) & 1) + 16 * (kap & 1) + (q & 15);
      f[j8] = (_Float16)W3[j * 32 + 16 * nh + col];
    }
    w3f[ks] = f;
  }

  float b2r[4];
#pragma unroll
  for (int t4 = 0; t4 < 4; t4++) b2r[t4] = b2[64 * nh + 16 * t4 + col];
  float k2v = 0.0f;
  if (col >= 1) {
    float om = omega[col] * (1.0f / CSND);
    k2v = om * om;
  }
  const float b3v = b3[16 * nh + col];

  float wsum = 0.0f;
  float xr[2][3];

  auto loadX = [&](int blk) {
    const float* xb = x + (size_t)blk * PB * 3;
#pragma unroll
    for (int hp = 0; hp < 2; hp++) {
      int p = pA + 16 * hp;
      xr[hp][0] = xb[3 * p]; xr[hp][1] = xb[3 * p + 1]; xr[hp][2] = xb[3 * p + 2];
    }
  };

  auto phaseA = [&]() {
    const int cbase = (g ^ pA) << 2;
    float wq[8];
#pragma unroll
    for (int u = 0; u < 8; u++)
      wq[u] = fmaf(wx[u], wx[u], fmaf(wy[u], wy[u], wz[u] * wz[u]));
#pragma unroll
    for (int hp = 0; hp < 2; hp++) {
      int p = pA + 16 * hp;
      float x0 = xr[hp][0], x1 = xr[hp][1], x2 = xr[hp][2];
      float t[8], s[8];
#pragma unroll
      for (int u = 0; u < 8; u++) {
        float z = fmaf(x0, wx[u], fmaf(x1, wy[u], fmaf(x2, wz[u], bB[u])));
        t[u] = mytanh(z);
        s[u] = 1.0f - t[u] * t[u];
      }
      uint4 q;
      q = make_uint4(pack2(t[0], t[1]), pack2(t[2], t[3]),
                     pack2(t[4], t[5]), pack2(t[6], t[7]));
      *(uint4*)&s_A[(p)       * 64 + cbase] = q;
      q = make_uint4(pack2(s[0]*wx[0], s[1]*wx[1]), pack2(s[2]*wx[2], s[3]*wx[3]),
                     pack2(s[4]*wx[4], s[5]*wx[5]), pack2(s[6]*wx[6], s[7]*wx[7]));
      *(uint4*)&s_A[(32 + p)  * 64 + cbase] = q;
      q = make_uint4(pack2(s[0]*wy[0], s[1]*wy[1]), pack2(s[2]*wy[2], s[3]*wy[3]),
                     pack2(s[4]*wy[4], s[5]*wy[5]), pack2(s[6]*wy[6], s[7]*wy[7]));
      *(uint4*)&s_A[(64 + p)  * 64 + cbase] = q;
      q = make_uint4(pack2(s[0]*wz[0], s[1]*wz[1]), pack2(s[2]*wz[2], s[3]*wz[3]),
                     pack2(s[4]*wz[4], s[5]*wz[5]), pack2(s[6]*wz[6], s[7]*wz[7]));
      *(uint4*)&s_A[(96 + p)  * 64 + cbase] = q;
      float c[8];
#pragma unroll
      for (int u = 0; u < 8; u++) c[u] = -2.0f * t[u] * s[u] * wq[u];
      q = make_uint4(pack2(c[0], c[1]), pack2(c[2], c[3]),
                     pack2(c[4], c[5]), pack2(c[6], c[7]));
      *(uint4*)&s_A[(128 + p) * 64 + cbase] = q;
    }
  };

  auto phaseDE = [&]() {
    const int pbase = (16 * ph + col) * 128;   // point row; (row&15)=col swizzle
    f32x4 dy = (f32x4){0.0f, 0.0f, 0.0f, 0.0f};
    f32x4 dl = (f32x4){0.0f, 0.0f, 0.0f, 0.0f};
#pragma unroll
    for (int ks = 0; ks < 4; ks++) {
      int pos = ((((ks << 2) + quad) ^ col) << 2);
      half8 afy = *(const half8*)&s_HG[pbase + pos];
      half8 afl = *(const half8*)&s_HG[pbase + 64 + pos];
      dy = __builtin_amdgcn_mfma_f32_16x16x32_f16(afy, w3f[ks], dy, 0, 0, 0);
      dl = __builtin_amdgcn_mfma_f32_16x16x32_f16(afl, w3f[ks], dl, 0, 0, 0);
    }
    if (col >= 1) {
#pragma unroll
      for (int r = 0; r < 4; r++) {
        float yv  = dy[r] + b3v;
        float res = fmaf(k2v, yv, dl[r]);
        wsum += res * res;
      }
    }
  };

  // ---- main loop ----
  loadX(blockIdx.x);
  bool first = true;
  for (int blk = blockIdx.x; blk < NBLK; blk += gridDim.x) {
    if (!first) phaseDE();          // D(i-1): reads s_HG (pre-b1)
    first = false;
    phaseA();                       // writes s_A
    __syncthreads();                // b1

    int nblk = blk + (int)gridDim.x;
    if (nblk < NBLK) loadX(nblk);   // prefetch x for next pass

    // ---- B(i): quadrant GEMM, STAGED to cap register pressure ----
    f32x4 bsum[4], acch[4], accc[4];
    {
      // stage 1: direction vectors v=1..3 -> accd, collapse to bsum
      f32x4 accd[3][4];
#pragma unroll
      for (int d = 0; d < 3; d++)
#pragma unroll
        for (int t4 = 0; t4 < 4; t4++)
          accd[d][t4] = (f32x4){0.0f, 0.0f, 0.0f, 0.0f};
#pragma unroll
      for (int d = 0; d < 3; d++) {
        const int rb = ((d + 1) * 32 + 16 * ph + col) * 64;
#pragma unroll
        for (int ks = 0; ks < 4; ks++) {
          half8 af = *(const half8*)&s_A[rb + ((((ks << 2) + quad) ^ col) << 2)];
          accd[d][0] = __builtin_amdgcn_mfma_f32_16x16x32_f16(af, w2f[0][ks], accd[d][0], 0, 0, 0);
          accd[d][1] = __builtin_amdgcn_mfma_f32_16x16x32_f16(af, w2f[1][ks], accd[d][1], 0, 0, 0);
          accd[d][2] = __builtin_amdgcn_mfma_f32_16x16x32_f16(af, w2f[2][ks], accd[d][2], 0, 0, 0);
          accd[d][3] = __builtin_amdgcn_mfma_f32_16x16x32_f16(af, w2f[3][ks], accd[d][3], 0, 0, 0);
        }
      }
#pragma unroll
      for (int t4 = 0; t4 < 4; t4++)
        bsum[t4] = accd[0][t4] * accd[0][t4] + accd[1][t4] * accd[1][t4]
                 + accd[2][t4] * accd[2][t4];
    }
    {
      // stage 2: h1 (v=0) and c1 (v=4)
#pragma unroll
      for (int t4 = 0; t4 < 4; t4++) {
        acch[t4] = (f32x4){0.0f, 0.0f, 0.0f, 0.0f};
        accc[t4] = (f32x4){0.0f, 0.0f, 0.0f, 0.0f};
      }
      const int rb0 = (16 * ph + col) * 64;
      const int rb4 = (128 + 16 * ph + col) * 64;
#pragma unroll
      for (int ks = 0; ks < 4; ks++) {
        int pos = ((((ks << 2) + quad) ^ col) << 2);
        half8 afh = *(const half8*)&s_A[rb0 + pos];
        half8 afc = *(const half8*)&s_A[rb4 + pos];
        acch[0] = __builtin_amdgcn_mfma_f32_16x16x32_f16(afh, w2f[0][ks], acch[0], 0, 0, 0);
        acch[1] = __builtin_amdgcn_mfma_f32_16x16x32_f16(afh, w2f[1][ks], acch[1], 0, 0, 0);
        acch[2] = __builtin_amdgcn_mfma_f32_16x16x32_f16(afh, w2f[2][ks], acch[2], 0, 0, 0);
        acch[3] = __builtin_amdgcn_mfma_f32_16x16x32_f16(afh, w2f[3][ks], acch[3], 0, 0, 0);
        accc[0] = __builtin_amdgcn_mfma_f32_16x16x32_f16(afc, w2f[0][ks], accc[0], 0, 0, 0);
        accc[1] = __builtin_amdgcn_mfma_f32_16x16x32_f16(afc, w2f[1][ks], accc[1], 0, 0, 0);
        accc[2] = __builtin_amdgcn_mfma_f32_16x16x32_f16(afc, w2f[2][ks], accc[2], 0, 0, 0);
        accc[3] = __builtin_amdgcn_mfma_f32_16x16x32_f16(afc, w2f[3][ks], accc[3], 0, 0, 0);
      }
    }

    // ---- C(i): layer-2 elementwise; paired-dword writes into permuted HG ----
#pragma unroll
    for (int r = 0; r < 4; r++) {
      int p = 16 * ph + (quad << 2) + r;
      float t2[4], gg[4];
#pragma unroll
      for (int t4 = 0; t4 < 4; t4++) {
        float z2 = acch[t4][r] + b2r[t4];
        float t  = mytanh(z2);
        float s2 = 1.0f - t * t;
        t2[t4] = t;
        gg[t4] = s2 * (accc[t4][r] - 2.0f * t * bsum[t4][r]);
      }
      int pb = p * 128;
#pragma unroll
      for (int pr = 0; pr < 2; pr++) {
        int q   = 32 * nh + 16 * pr + col;
        int pos = (((q >> 2) ^ (p & 15)) << 2) + (q & 3);
        s_HG[pb + pos]      = pack2(t2[2 * pr], t2[2 * pr + 1]);
        s_HG[pb + 64 + pos] = pack2(gg[2 * pr], gg[2 * pr + 1]);
      }
    }
    __syncthreads();                // b2
  }
  phaseDE();                        // epilogue D for the final pass

  // ---- final: wave reduce, one atomic per wave ----
#pragma unroll
  for (int off = 32; off > 0; off >>= 1)
    wsum += __shfl_down(wsum, off, 64);
  if (l == 0)
    atomicAdd(out, wsum * (1.0f / ((float)NPTS * (float)(FCH - 1))));
}

extern "C" void kernel_launch(void* const* d_in, const int* in_sizes, int n_in,
                              void* d_out, int out_size, void* d_ws, size_t ws_size,
                              hipStream_t stream) {
  const float* x     = (const float*)d_in[0];
  const float* omega = (const float*)d_in[1];
  const float* W1    = (const float*)d_in[2];
  const float* b1    = (const float*)d_in[3];
  const float* W2    = (const float*)d_in[4];
  const float* b2    = (const float*)d_in[5];
  const float* W3    = (const float*)d_in[6];
  const float* b3    = (const float*)d_in[7];
  float* out = (float*)d_out;

  (void)hipMemsetAsync(out, 0, sizeof(float), stream);
  helmholtz_kernel<<<GRID, BLOCK, 0, stream>>>(x, omega, W1, b1, W2, b2, W3, b3, out);
}